// Round 4
// baseline (1143.968 us; speedup 1.0000x reference)
//
#include <hip/hip_runtime.h>

typedef unsigned short u16;
typedef unsigned int   u32;
typedef __attribute__((ext_vector_type(8))) __bf16 bf16x8;
typedef __attribute__((ext_vector_type(4))) float  f32x4;

#define BQ   8
#define SQ   4096
#define NHQ  16
#define HIDD 1024
#define TOKN 32768

__device__ __forceinline__ u16 f2bf(float f){
  u32 u = __builtin_bit_cast(u32, f);
  u += 0x7fffu + ((u >> 16) & 1u);
  return (u16)(u >> 16);
}
__device__ __forceinline__ float bf2f(u16 h){
  return __builtin_bit_cast(float, (u32)h << 16);
}
#define MFMA(a,b,c) __builtin_amdgcn_mfma_f32_16x16x32_bf16((a),(b),(c),0,0,0)

// ---------------- fp32 -> bf16 cast (weights) ----------------
__global__ __launch_bounds__(256) void k_cast(const float* __restrict__ in, u16* __restrict__ o){
  int i = blockIdx.x * 256 + threadIdx.x;
  float4 v = ((const float4*)in)[i];
  ushort4 r;
  r.x = f2bf(v.x); r.y = f2bf(v.y); r.z = f2bf(v.z); r.w = f2bf(v.w);
  ((ushort4*)o)[i] = r;
}

// ---------------- LayerNorm + cast x / x_norm ----------------
__global__ __launch_bounds__(256) void k_ln(const float* __restrict__ x, const float* __restrict__ g,
    const float* __restrict__ be, u16* __restrict__ xbf, u16* __restrict__ xnbf){
  const int row = blockIdx.x, t = threadIdx.x;
  const float4 v = ((const float4*)(x + (size_t)row * HIDD))[t];
  float s  = v.x + v.y + v.z + v.w;
  float ss = v.x*v.x + v.y*v.y + v.z*v.z + v.w*v.w;
  #pragma unroll
  for (int o = 1; o < 64; o <<= 1){ s += __shfl_xor(s, o); ss += __shfl_xor(ss, o); }
  __shared__ float sm[8];
  const int lane = t & 63, wid = t >> 6;
  if (lane == 0){ sm[wid] = s; sm[wid + 4] = ss; }
  __syncthreads();
  s  = sm[0] + sm[1] + sm[2] + sm[3];
  ss = sm[4] + sm[5] + sm[6] + sm[7];
  const float mu   = s * (1.f / 1024.f);
  const float var  = ss * (1.f / 1024.f) - mu * mu;
  const float rstd = rsqrtf(var + 1e-12f);
  const float4 gg = ((const float4*)g)[t];
  const float4 bb = ((const float4*)be)[t];
  ushort4 xo, no;
  xo.x = f2bf(v.x); no.x = f2bf((v.x - mu) * rstd * gg.x + bb.x);
  xo.y = f2bf(v.y); no.y = f2bf((v.y - mu) * rstd * gg.y + bb.y);
  xo.z = f2bf(v.z); no.z = f2bf((v.z - mu) * rstd * gg.z + bb.z);
  xo.w = f2bf(v.w); no.w = f2bf((v.w - mu) * rstd * gg.w + bb.w);
  ((ushort4*)(xbf  + (size_t)row * HIDD))[t] = xo;
  ((ushort4*)(xnbf + (size_t)row * HIDD))[t] = no;
}

// ---------------- 8-phase 256x256 NT GEMM: C = A[M,K] * W[N,K]^T + bias (+resid) ----------------
// 8 waves (2Mx4N), BK=64. Per K-tile: 4 phases, each = one 128x128 C-quadrant x K=64.
// Quadrant order (0,0),(1,0),(1,1),(0,1) -> A/B frag register reuse on alternate phases.
// LDS: 8 slots x 16KB, granule-major [g][128 rows] with physrow = (row&~7)|((row&7)^g)
// (r1/r3-C measured zero-conflict read/write class). Reg-staged: per phase
// {vmcnt(2); ds_write half-tile (loaded 2 phases ago) into dead slot; issue next 2 loads;
//  lgkmcnt(0); barrier; setprio1; 16 MFMA; setprio0; barrier}. vmcnt never 0 in loop.
template<int RES>
__global__ __launch_bounds__(512, 2) void k_gemm8p(const u16* __restrict__ A,
    const u16* __restrict__ W, const float* __restrict__ bias,
    const float* __restrict__ resid, u16* __restrict__ outb, float* __restrict__ outf){
  __shared__ union {
    u16 st[8][8192];      // slotA(I,d)=d*4+I, slotB(J,d)=d*4+2+J
    float cep[8][544];    // per-wave [16][34] f32 epilogue staging
  } sm;

  const int bid = blockIdx.x;
  const int wg = ((bid & 7) << 6) + (bid >> 3);   // XCD-chunked swizzle (512 % 8 == 0)
  const int m0 = (wg >> 2) << 8;
  const int n0 = (wg & 3) << 8;

  const int tid = threadIdx.x, lane = tid & 63, wid = tid >> 6;
  const int ln15 = lane & 15, hi = lane >> 4;
  const int wr = wid >> 2, wc = wid & 3;
  const int l7 = lane & 7;

  // staging geometry: chunk gc = i*512 + tid -> (row = gc>>3, g = gc&7)
  int srow[2], sg[2], soff[2];
  #pragma unroll
  for (int i = 0; i < 2; i++){
    int gc = (i << 9) + tid;
    srow[i] = gc >> 3; sg[i] = gc & 7;
    soff[i] = (sg[i] << 10) + (((srow[i] & 120) | ((srow[i] & 7) ^ sg[i])) << 3);
  }
  const int abase = (wr << 6) + (ln15 & 8);
  const int bbase = (wc << 5) + (ln15 & 8);

  f32x4 acc[2][2][4][2] = {};
  bf16x8 af[4][2];
  bf16x8 bq[2][2];
  uint4 pr[2][2];

  #define GLD(dst, src, rowoff, koff) \
    { dst[0] = *(const uint4*)((src) + (size_t)((rowoff) + srow[0]) * HIDD + (koff) + (sg[0] << 3)); \
      dst[1] = *(const uint4*)((src) + (size_t)((rowoff) + srow[1]) * HIDD + (koff) + (sg[1] << 3)); }
  #define WSL(slot, r) \
    { *(uint4*)&sm.st[slot][soff[0]] = r[0]; *(uint4*)&sm.st[slot][soff[1]] = r[1]; }
  #define FRA(slot, m, g) (*(const bf16x8*)&sm.st[slot][((g) << 10) + ((abase + ((m) << 4)) << 3) + ((l7 ^ (g)) << 3)])
  #define FRB(slot, n, g) (*(const bf16x8*)&sm.st[slot][((g) << 10) + ((bbase + ((n) << 4)) << 3) + ((l7 ^ (g)) << 3)])
  #define RDA(slot) \
    _Pragma("unroll") \
    for (int m = 0; m < 4; m++){ af[m][0] = FRA(slot, m, hi); af[m][1] = FRA(slot, m, hi + 4); }
  #define RDB(slot) \
    _Pragma("unroll") \
    for (int n = 0; n < 2; n++){ bq[n][0] = FRB(slot, n, hi); bq[n][1] = FRB(slot, n, hi + 4); }
  #define CLUSTER(I, J) \
    __builtin_amdgcn_s_setprio(1); \
    _Pragma("unroll") \
    for (int m = 0; m < 4; m++) \
      _Pragma("unroll") \
      for (int n = 0; n < 2; n++){ \
        acc[I][J][m][n] = MFMA(af[m][0], bq[n][0], acc[I][J][m][n]); \
        acc[I][J][m][n] = MFMA(af[m][1], bq[n][1], acc[I][J][m][n]); \
      } \
    __builtin_amdgcn_s_setprio(0);
  #define BAR do { asm volatile("" ::: "memory"); __builtin_amdgcn_s_barrier(); asm volatile("" ::: "memory"); } while(0)
  #define LGKM0 asm volatile("s_waitcnt lgkmcnt(0)" ::: "memory")
  #define VM(n) asm volatile("s_waitcnt vmcnt(" #n ")" ::: "memory")

  // ---- prologue: fill K-tiles 0 (slots 0-3) and 1 (slots 4-7); prime pipeline regs ----
  #pragma unroll
  for (int tt = 0; tt < 2; ++tt){
    uint4 h0[2], h1[2], h2[2], h3[2];
    GLD(h0, A, m0,       tt << 6);
    GLD(h1, A, m0 + 128, tt << 6);
    GLD(h2, W, n0,       tt << 6);
    GLD(h3, W, n0 + 128, tt << 6);
    VM(0);
    WSL((tt << 2) + 0, h0); WSL((tt << 2) + 1, h1);
    WSL((tt << 2) + 2, h2); WSL((tt << 2) + 3, h3);
  }
  GLD(pr[0], A, m0,       64);   // At(1)  (consumed kt=0 PH0, rewrite of prologue data)
  GLD(pr[1], W, n0 + 128, 64);   // Bb(1)  (consumed kt=0 PH1)
  LGKM0;
  BAR;

  const int NT = HIDD / 64;   // 16
  for (int kt = 0; kt < NT; ++kt){
    const int d4 = (kt & 1) << 2, e4 = d4 ^ 4;
    const int kl = (kt + 2 < NT ? kt + 2 : NT - 1) << 6;
    // ---- PH0: quad(0,0) — 12 ds_reads; W At(kt+1); L Bt(kt+2) ----
    RDA(d4 + 0);
    RDB(d4 + 2);
    VM(2);
    WSL(e4 + 0, pr[0]);
    GLD(pr[0], W, n0, kl);
    LGKM0;
    BAR;
    CLUSTER(0, 0);
    BAR;
    // ---- PH1: quad(1,0) — 8 ds_reads (bq reuse); W Bb(kt+1); L Ab(kt+2) ----
    RDA(d4 + 1);
    VM(2);
    WSL(e4 + 3, pr[1]);
    GLD(pr[1], A, m0 + 128, kl);
    LGKM0;
    BAR;
    CLUSTER(1, 0);
    BAR;
    // ---- PH2: quad(1,1) — 4 ds_reads (af reuse); W Bt(kt+2); L At(kt+2) ----
    RDB(d4 + 3);
    VM(2);
    WSL(d4 + 2, pr[0]);
    GLD(pr[0], A, m0, kl);
    LGKM0;
    BAR;
    CLUSTER(1, 1);
    BAR;
    // ---- PH3: quad(0,1) — 8 ds_reads (bq reuse); W Ab(kt+2); L Bb(kt+2) ----
    RDA(d4 + 0);
    VM(2);
    WSL(d4 + 1, pr[1]);
    GLD(pr[1], W, n0 + 128, kl);
    LGKM0;
    BAR;
    CLUSTER(0, 1);
    BAR;
  }

  // ---- epilogue ----
  VM(0); LGKM0;
  BAR;

  float bn[2][2];
  #pragma unroll
  for (int J = 0; J < 2; J++)
    #pragma unroll
    for (int n = 0; n < 2; n++)
      bn[J][n] = bias[n0 + (J << 7) + (wc << 5) + (n << 4) + ln15];

  if constexpr (RES){
    #pragma unroll
    for (int I = 0; I < 2; I++)
      #pragma unroll
      for (int J = 0; J < 2; J++)
        #pragma unroll
        for (int m = 0; m < 4; m++)
          #pragma unroll
          for (int n = 0; n < 2; n++)
            #pragma unroll
            for (int r = 0; r < 4; r++){
              size_t idx = (size_t)(m0 + (I << 7) + (wr << 6) + (m << 4) + (hi << 2) + r) * HIDD
                         + n0 + (J << 7) + (wc << 5) + (n << 4) + ln15;
              outf[idx] = acc[I][J][m][n][r] + bn[J][n] + resid[idx];
            }
  } else {
    float* cw = &sm.cep[wid][0];   // [16][34]
    const int r16 = lane >> 2, cg = lane & 3;
    #pragma unroll
    for (int I = 0; I < 2; I++)
      #pragma unroll
      for (int J = 0; J < 2; J++)
        #pragma unroll
        for (int m = 0; m < 4; m++){
          #pragma unroll
          for (int n = 0; n < 2; n++)
            #pragma unroll
            for (int r = 0; r < 4; r++)
              cw[((hi << 2) + r) * 34 + (n << 4) + ln15] = acc[I][J][m][n][r] + bn[J][n];
          u32 ro[4];
          #pragma unroll
          for (int p = 0; p < 4; p++){
            float v0 = cw[r16 * 34 + (cg << 3) + 2 * p];
            float v1 = cw[r16 * 34 + (cg << 3) + 2 * p + 1];
            ro[p] = (u32)f2bf(v0) | ((u32)f2bf(v1) << 16);
          }
          uint4 o; o.x = ro[0]; o.y = ro[1]; o.z = ro[2]; o.w = ro[3];
          *(uint4*)&outb[(size_t)(m0 + (I << 7) + (wr << 6) + (m << 4) + r16) * HIDD
                         + n0 + (J << 7) + (wc << 5) + (cg << 3)] = o;
        }
  }
  #undef GLD
  #undef WSL
  #undef FRA
  #undef FRB
  #undef RDA
  #undef RDB
  #undef CLUSTER
  #undef BAR
  #undef LGKM0
  #undef VM
}

// ---------------- elu + L2 norm over head_dim (in-place, q) ----------------
__global__ __launch_bounds__(256) void k_elunorm(u16* __restrict__ q){
  size_t idx = (size_t)blockIdx.x * 256 + threadIdx.x;
  uint4 u = ((const uint4*)q)[idx];
  u32 uu[4] = {u.x, u.y, u.z, u.w};
  float e[8]; float ss = 0.f;
  #pragma unroll
  for (int i = 0; i < 4; i++){
    float f0 = bf2f((u16)(uu[i] & 0xffff));
    float f1 = bf2f((u16)(uu[i] >> 16));
    f0 = f0 > 0.f ? f0 : expm1f(f0);
    f1 = f1 > 0.f ? f1 : expm1f(f1);
    e[2*i] = f0; e[2*i+1] = f1;
    ss += f0 * f0 + f1 * f1;
  }
  ss += __shfl_xor(ss, 1); ss += __shfl_xor(ss, 2); ss += __shfl_xor(ss, 4);
  float rn = rsqrtf(ss);
  u32 ro[4];
  #pragma unroll
  for (int i = 0; i < 4; i++)
    ro[i] = (u32)f2bf(e[2*i] * rn) | ((u32)f2bf(e[2*i+1] * rn) << 16);
  uint4 o; o.x = ro[0]; o.y = ro[1]; o.z = ro[2]; o.w = ro[3];
  ((uint4*)q)[idx] = o;
}

// ---------------- transpose [B,S,H,64] -> [B,H,64,S], optional elu+L2norm ----------------
template<int ELU>
__global__ __launch_bounds__(256) void k_transpose(const u16* __restrict__ in, u16* __restrict__ outp){
  __shared__ float tile[64][65];
  __shared__ float pr[64][4];
  __shared__ float rn[64];
  const int sb = blockIdx.x << 6, h = blockIdx.y, b = blockIdx.z;
  const int t = threadIdx.x;
  {
    const int tok = t >> 2, q = t & 3;
    const u16* src = in + (size_t)(b * SQ + sb + tok) * HIDD + (h << 6) + (q << 4);
    uint4 u0 = *(const uint4*)src;
    uint4 u1 = *(const uint4*)(src + 8);
    u32 uu[8] = {u0.x, u0.y, u0.z, u0.w, u1.x, u1.y, u1.z, u1.w};
    float ss = 0.f;
    #pragma unroll
    for (int i = 0; i < 8; i++){
      float f0 = bf2f((u16)(uu[i] & 0xffff));
      float f1 = bf2f((u16)(uu[i] >> 16));
      if (ELU){
        f0 = f0 > 0.f ? f0 : expm1f(f0);
        f1 = f1 > 0.f ? f1 : expm1f(f1);
        ss += f0 * f0 + f1 * f1;
      }
      tile[tok][(q << 4) + 2*i]     = f0;
      tile[tok][(q << 4) + 2*i + 1] = f1;
    }
    if (ELU) pr[tok][q] = ss;
  }
  __syncthreads();
  if (ELU){
    if (t < 64) rn[t] = rsqrtf(pr[t][0] + pr[t][1] + pr[t][2] + pr[t][3]);
    __syncthreads();
  }
  const int d = t >> 2, sq2 = (t & 3) << 4;
  u16* dst = outp + ((size_t)(b * NHQ + h) * 64 + d) * SQ + sb + sq2;
  u32 ro[8];
  #pragma unroll
  for (int i = 0; i < 8; i++){
    float v0 = tile[sq2 + 2*i][d];
    float v1 = tile[sq2 + 2*i + 1][d];
    if (ELU){ v0 *= rn[sq2 + 2*i]; v1 *= rn[sq2 + 2*i + 1]; }
    ro[i] = (u32)f2bf(v0) | ((u32)f2bf(v1) << 16);
  }
  uint4 o0; o0.x = ro[0]; o0.y = ro[1]; o0.z = ro[2]; o0.w = ro[3];
  uint4 o1; o1.x = ro[4]; o1.y = ro[5]; o1.z = ro[6]; o1.w = ro[7];
  *(uint4*)dst = o0;
  *(uint4*)(dst + 8) = o1;
}

// ---------------- kv: per (b,h)  kvT[e][d] = (1/8) * sum_s v[s][e] ek[s][d] ----------------
__global__ __launch_bounds__(256) void k_kv(const u16* __restrict__ vT, const u16* __restrict__ ekT,
                                            u16* __restrict__ kvT){
  const int bh = blockIdx.x;
  const u16* Av = vT  + (size_t)bh * 64 * SQ;
  const u16* Bk = ekT + (size_t)bh * 64 * SQ;
  const int lane = threadIdx.x & 63, wid = threadIdx.x >> 6;
  const int ln15 = lane & 15, hi = lane >> 4;
  f32x4 acc[4][4] = {};
  const int kb = wid << 10;
  for (int ks = 0; ks < 32; ++ks){
    const int k0 = kb + (ks << 5) + (hi << 3);
    bf16x8 af[4], bfr[4];
    #pragma unroll
    for (int m = 0; m < 4; m++) af[m]  = *(const bf16x8*)(Av + (size_t)((m << 4) + ln15) * SQ + k0);
    #pragma unroll
    for (int n = 0; n < 4; n++) bfr[n] = *(const bf16x8*)(Bk + (size_t)((n << 4) + ln15) * SQ + k0);
    #pragma unroll
    for (int m = 0; m < 4; m++)
      #pragma unroll
      for (int n = 0; n < 4; n++)
        acc[m][n] = MFMA(af[m], bfr[n], acc[m][n]);
  }
  __shared__ float red[64][64];
  for (int w = 0; w < 4; ++w){
    if (wid == w){
      #pragma unroll
      for (int m = 0; m < 4; m++)
        #pragma unroll
        for (int n = 0; n < 4; n++)
          #pragma unroll
          for (int r = 0; r < 4; r++){
            int row = (m << 4) + (hi << 2) + r;
            int col = (n << 4) + ln15;
            if (w == 0) red[row][col] = acc[m][n][r];
            else        red[row][col] += acc[m][n][r];
          }
    }
    __syncthreads();
  }
  u16* dst = kvT + (size_t)bh * 4096;
  const int tt = threadIdx.x;
  #pragma unroll
  for (int i = 0; i < 16; i++){
    int idx = tt * 16 + i;
    dst[idx] = f2bf(red[idx >> 6][idx & 63] * 0.125f);
  }
}

// ---------------- ctx: per (b,h,sblock) ctx[s][e] = sum_d eq[s][d] * kv[d][e] ----------------
__global__ __launch_bounds__(256) void k_ctx(const u16* __restrict__ eq, const u16* __restrict__ kvT,
                                             u16* __restrict__ ctx){
  __shared__ u16 Alds[1024 * 8];
  __shared__ u16 Blds[512 * 8];
  const int sb = blockIdx.x << 7;
  const int h = blockIdx.y, b = blockIdx.z;
  const int bh = (b << 4) + h;
  const int t = threadIdx.x, lane = t & 63, wid = t >> 6;
  const int ln15 = lane & 15, hi = lane >> 4;
  // reg-stage into LDS (simple, small kernel)
  {
    uint4 va[4]; uint4 vb[2];
    #pragma unroll
    for (int i = 0; i < 4; i++){
      int c = (wid << 6) + (i << 8) + lane;
      int g = c >> 7, row = c & 127;
      va[i] = *(const uint4*)(eq + (size_t)(b * SQ + sb + row) * HIDD + (h << 6) + g * 8);
    }
    #pragma unroll
    for (int i = 0; i < 2; i++){
      int c = (wid << 6) + (i << 8) + lane;
      int g = c >> 6, row = c & 63;
      vb[i] = *(const uint4*)(kvT + (size_t)bh * 4096 + (row << 6) + g * 8);
    }
    #pragma unroll
    for (int i = 0; i < 4; i++)
      *(uint4*)&Alds[((wid << 6) + (i << 8) + lane) * 8] = va[i];
    #pragma unroll
    for (int i = 0; i < 2; i++)
      *(uint4*)&Blds[((wid << 6) + (i << 8) + lane) * 8] = vb[i];
  }
  __syncthreads();
  f32x4 acc[2][4] = {};
  #pragma unroll
  for (int k2 = 0; k2 < 2; k2++){
    const int g = (k2 << 2) + hi;
    bf16x8 af[2], bfr[4];
    #pragma unroll
    for (int m = 0; m < 2; m++) af[m]  = *(const bf16x8*)&Alds[((g << 7) + (wid << 5) + (m << 4) + ln15) * 8];
    #pragma unroll
    for (int n = 0; n < 4; n++) bfr[n] = *(const bf16x8*)&Blds[((g << 6) + (n << 4) + ln15) * 8];
    #pragma unroll
    for (int m = 0; m < 2; m++)
      #pragma unroll
      for (int n = 0; n < 4; n++)
        acc[m][n] = MFMA(af[m], bfr[n], acc[m][n]);
  }
  #pragma unroll
  for (int m = 0; m < 2; m++)
    #pragma unroll
    for (int n = 0; n < 4; n++)
      #pragma unroll
      for (int r = 0; r < 4; r++){
        int srow = sb + (wid << 5) + (m << 4) + (hi << 2) + r;
        int col  = (n << 4) + ln15;
        ctx[(size_t)(b * SQ + srow) * HIDD + (h << 6) + col] = f2bf(acc[m][n][r]);
      }
}

extern "C" void kernel_launch(void* const* d_in, const int* in_sizes, int n_in,
                              void* d_out, int out_size, void* d_ws, size_t ws_size,
                              hipStream_t stream){
  const float* x   = (const float*)d_in[0];
  const float* lng = (const float*)d_in[2];
  const float* lnb = (const float*)d_in[3];
  const float* Wq  = (const float*)d_in[4];
  const float* bq  = (const float*)d_in[5];
  const float* Wk  = (const float*)d_in[6];
  const float* bk  = (const float*)d_in[7];
  const float* Wv  = (const float*)d_in[8];
  const float* bv  = (const float*)d_in[9];
  const float* Wo  = (const float*)d_in[10];
  const float* bo  = (const float*)d_in[11];
  float* out = (float*)d_out;

  char* w = (char*)d_ws;
  const size_t MB = 1ull << 20;
  u16* wqb  = (u16*)(w + 0   * MB);
  u16* wkb  = (u16*)(w + 2   * MB);
  u16* wvb  = (u16*)(w + 4   * MB);
  u16* wob  = (u16*)(w + 6   * MB);
  u16* xbf  = (u16*)(w + 8   * MB);
  u16* xnbf = (u16*)(w + 72  * MB);
  u16* qb   = (u16*)(w + 136 * MB);
  u16* kb   = (u16*)(w + 200 * MB);
  u16* vb   = (u16*)(w + 264 * MB);
  u16* kvT  = (u16*)(w + 328 * MB);
  u16* ekT = xnbf;
  u16* vT  = xbf;
  u16* ctx = kb;

  k_cast<<<1024, 256, 0, stream>>>(Wq, wqb);
  k_cast<<<1024, 256, 0, stream>>>(Wk, wkb);
  k_cast<<<1024, 256, 0, stream>>>(Wv, wvb);
  k_cast<<<1024, 256, 0, stream>>>(Wo, wob);
  k_ln<<<TOKN, 256, 0, stream>>>(x, lng, lnb, xbf, xnbf);
  k_gemm8p<0><<<512, 512, 0, stream>>>(xnbf, wqb, bq, nullptr, qb, nullptr);
  k_gemm8p<0><<<512, 512, 0, stream>>>(xbf,  wkb, bk, nullptr, kb, nullptr);
  k_gemm8p<0><<<512, 512, 0, stream>>>(xbf,  wvb, bv, nullptr, vb, nullptr);
  k_elunorm<<<16384, 256, 0, stream>>>(qb);
  k_transpose<1><<<dim3(64, 16, 8), 256, 0, stream>>>(kb, ekT);
  k_transpose<0><<<dim3(64, 16, 8), 256, 0, stream>>>(vb, vT);
  k_kv<<<128, 256, 0, stream>>>(vT, ekT, kvT);
  k_ctx<<<dim3(32, 16, 8), 256, 0, stream>>>(qb, kvT, ctx);
  k_gemm8p<1><<<512, 512, 0, stream>>>(ctx, wob, bo, x, nullptr, out);

  (void)in_sizes; (void)n_in; (void)out_size; (void)ws_size;
}

// Round 5
// 910.194 us; speedup vs baseline: 1.2568x; 1.2568x over previous
//
#include <hip/hip_runtime.h>

typedef unsigned short u16;
typedef unsigned int   u32;
typedef __attribute__((ext_vector_type(8))) __bf16 bf16x8;
typedef __attribute__((ext_vector_type(4))) float  f32x4;

#define BQ   8
#define SQ   4096
#define NHQ  16
#define HIDD 1024
#define TOKN 32768

__device__ __forceinline__ u16 f2bf(float f){
  u32 u = __builtin_bit_cast(u32, f);
  u += 0x7fffu + ((u >> 16) & 1u);
  return (u16)(u >> 16);
}
__device__ __forceinline__ float bf2f(u16 h){
  return __builtin_bit_cast(float, (u32)h << 16);
}
__device__ __forceinline__ void gl16(const void* g, void* l){
  __builtin_amdgcn_global_load_lds((const __attribute__((address_space(1))) void*)g,
                                   (__attribute__((address_space(3))) void*)l, 16, 0, 0);
}
#define MFMA(a,b,c) __builtin_amdgcn_mfma_f32_16x16x32_bf16((a),(b),(c),0,0,0)

// ---------------- fp32 -> bf16 cast (weights) ----------------
__global__ __launch_bounds__(256) void k_cast(const float* __restrict__ in, u16* __restrict__ o){
  int i = blockIdx.x * 256 + threadIdx.x;
  float4 v = ((const float4*)in)[i];
  ushort4 r;
  r.x = f2bf(v.x); r.y = f2bf(v.y); r.z = f2bf(v.z); r.w = f2bf(v.w);
  ((ushort4*)o)[i] = r;
}

// ---------------- LayerNorm + cast x / x_norm ----------------
__global__ __launch_bounds__(256) void k_ln(const float* __restrict__ x, const float* __restrict__ g,
    const float* __restrict__ be, u16* __restrict__ xbf, u16* __restrict__ xnbf){
  const int row = blockIdx.x, t = threadIdx.x;
  const float4 v = ((const float4*)(x + (size_t)row * HIDD))[t];
  float s  = v.x + v.y + v.z + v.w;
  float ss = v.x*v.x + v.y*v.y + v.z*v.z + v.w*v.w;
  #pragma unroll
  for (int o = 1; o < 64; o <<= 1){ s += __shfl_xor(s, o); ss += __shfl_xor(ss, o); }
  __shared__ float sm[8];
  const int lane = t & 63, wid = t >> 6;
  if (lane == 0){ sm[wid] = s; sm[wid + 4] = ss; }
  __syncthreads();
  s  = sm[0] + sm[1] + sm[2] + sm[3];
  ss = sm[4] + sm[5] + sm[6] + sm[7];
  const float mu   = s * (1.f / 1024.f);
  const float var  = ss * (1.f / 1024.f) - mu * mu;
  const float rstd = rsqrtf(var + 1e-12f);
  const float4 gg = ((const float4*)g)[t];
  const float4 bb = ((const float4*)be)[t];
  ushort4 xo, no;
  xo.x = f2bf(v.x); no.x = f2bf((v.x - mu) * rstd * gg.x + bb.x);
  xo.y = f2bf(v.y); no.y = f2bf((v.y - mu) * rstd * gg.y + bb.y);
  xo.z = f2bf(v.z); no.z = f2bf((v.z - mu) * rstd * gg.z + bb.z);
  xo.w = f2bf(v.w); no.w = f2bf((v.w - mu) * rstd * gg.w + bb.w);
  ((ushort4*)(xbf  + (size_t)row * HIDD))[t] = xo;
  ((ushort4*)(xnbf + (size_t)row * HIDD))[t] = no;
}

// ---------------- 8-phase 256x256 NT GEMM: C = A[M,K] * W[N,K]^T + bias (+resid) ----------------
// 8 waves (2Mx4N within a 128x128 quadrant), BK=64. Per K-tile: 4 phases; phase j computes
// quadrant q(j) in order (0,0),(1,0),(1,1),(0,1) (A-frags reused ph1->ph2, B ph0->ph1, ph2->ph3).
// Quadrant (qi,qj) reads ONLY A-half qi and B-half qj -> half-tile prefetch staggers:
// phase (T,j) issues half h(j) of tile T+1 (order At,Bt,Ab,Bb) via 2 global_load_lds
// straight into its granule-major slot; counted vmcnt(4) BEFORE the barrier (none at ph2,
// never 0 in loop). LDS slots: [buf][At,Ab,Bt,Bb] 8 x 16KB, granule-major
// chunk = g*128 + row (r1-measured ZERO-conflict class for both gl_lds writes and frag reads).
template<int RES>
__global__ __launch_bounds__(512, 2) void k_gemm8p(const u16* __restrict__ A,
    const u16* __restrict__ W, const float* __restrict__ bias,
    const float* __restrict__ resid, u16* __restrict__ outb, float* __restrict__ outf){
  __shared__ union {
    u16 st[8][8192];      // slot = buf*4 + {0:At,1:Ab,2:Bt,3:Bb}; u16 off = g*1024 + row*8
    float cep[8][544];    // per-wave [16][34] f32 epilogue staging
  } sm;

  const int bid = blockIdx.x;
  const int wg = ((bid & 7) << 6) + (bid >> 3);   // XCD-chunked swizzle (512 % 8 == 0)
  const int m0 = (wg >> 2) << 8;
  const int n0 = (wg & 3) << 8;

  const int tid = threadIdx.x, lane = tid & 63, wid = tid >> 6;
  const int ln15 = lane & 15, hi = lane >> 4;
  const int wr = wid >> 2, wc = wid & 3;
  const int arow = (wr << 6) + ln15;    // A row within half (0..127), + m*16
  const int brow = (wc << 5) + ln15;    // B row within half (0..127), + n*16

  // stage one 128x64 half-tile (16KB) into slot: 2 x gl16/thread, lane-linear dest.
  // chunk c = i*512 + tid -> (g = c>>7, row = c&127); dest u16 off = c*8.
  auto stageH = [&](int slot, const u16* __restrict__ src, int rowoff, int kt){
    #pragma unroll
    for (int i = 0; i < 2; i++){
      const int c = (i << 9) + tid;
      const int row = c & 127, g = c >> 7;
      gl16(src + (size_t)(rowoff + row) * HIDD + (kt << 6) + (g << 3),
           &sm.st[slot][(i << 12) + (tid << 3)]);
    }
  };

  f32x4 acc[2][2][4][2] = {};
  bf16x8 a_[4][2], b_[2][2];

  #define RDA(buf, QI) \
    _Pragma("unroll") \
    for (int m = 0; m < 4; m++){ \
      a_[m][0] = *(const bf16x8*)&sm.st[((buf) << 2) + (QI)][(hi << 10) + ((arow + (m << 4)) << 3)]; \
      a_[m][1] = *(const bf16x8*)&sm.st[((buf) << 2) + (QI)][((hi + 4) << 10) + ((arow + (m << 4)) << 3)]; \
    }
  #define RDB(buf, QJ) \
    _Pragma("unroll") \
    for (int n = 0; n < 2; n++){ \
      b_[n][0] = *(const bf16x8*)&sm.st[((buf) << 2) + 2 + (QJ)][(hi << 10) + ((brow + (n << 4)) << 3)]; \
      b_[n][1] = *(const bf16x8*)&sm.st[((buf) << 2) + 2 + (QJ)][((hi + 4) << 10) + ((brow + (n << 4)) << 3)]; \
    }
  #define CLUSTER(QI, QJ) \
    __builtin_amdgcn_s_setprio(1); \
    _Pragma("unroll") \
    for (int m = 0; m < 4; m++) \
      _Pragma("unroll") \
      for (int n = 0; n < 2; n++){ \
        acc[QI][QJ][m][n] = MFMA(a_[m][0], b_[n][0], acc[QI][QJ][m][n]); \
        acc[QI][QJ][m][n] = MFMA(a_[m][1], b_[n][1], acc[QI][QJ][m][n]); \
      } \
    __builtin_amdgcn_s_setprio(0);
  #define BAR do { asm volatile("" ::: "memory"); __builtin_amdgcn_s_barrier(); asm volatile("" ::: "memory"); } while(0)
  #define VM(n) asm volatile("s_waitcnt vmcnt(" #n ")" ::: "memory")

  // ---- prologue: tile 0 into buf0 slots; one-time full drain ----
  stageH(0, A, m0,       0);
  stageH(1, A, m0 + 128, 0);
  stageH(2, W, n0,       0);
  stageH(3, W, n0 + 128, 0);
  VM(0);
  BAR;

  const int NT = HIDD / 64;   // 16
  for (int kt = 0; kt < NT; ++kt){
    const int b = kt & 1, nbs = (b ^ 1) << 2;
    const int ktn = (kt + 1 < NT) ? kt + 1 : kt;   // tail: harmless re-stage into dead slots
    // ---- ph0: q(0,0) reads At,Bt; issue At(kt+1) ----
    RDA(b, 0); RDB(b, 0);
    stageH(nbs + 0, A, m0, ktn);
    VM(4);                      // next phase reads Ab(kt) (issued 2 phases back)
    BAR;
    CLUSTER(0, 0);
    BAR;
    // ---- ph1: q(1,0) reads Ab (B reused); issue Bt(kt+1) ----
    RDA(b, 1);
    stageH(nbs + 2, W, n0, ktn);
    VM(4);                      // next phase reads Bb(kt)
    BAR;
    CLUSTER(1, 0);
    BAR;
    // ---- ph2: q(1,1) reads Bb (A reused); issue Ab(kt+1) ----
    RDB(b, 1);
    stageH(nbs + 1, A, m0 + 128, ktn);
    BAR;                        // next phase reads At(kt) (ancient) -> no vmcnt
    CLUSTER(1, 1);
    BAR;
    // ---- ph3: q(0,1) reads At (B reused); issue Bb(kt+1) ----
    RDA(b, 0);
    stageH(nbs + 3, W, n0 + 128, ktn);
    VM(4);                      // next K-tile ph0 reads At,Bt(kt+1) = oldest 4 of 8
    BAR;
    CLUSTER(0, 1);
    BAR;
  }

  // ---- epilogue (drain tail stages before LDS reuse) ----
  VM(0);
  BAR;

  float bn[2][2];
  #pragma unroll
  for (int J = 0; J < 2; J++)
    #pragma unroll
    for (int n = 0; n < 2; n++)
      bn[J][n] = bias[n0 + (J << 7) + (wc << 5) + (n << 4) + ln15];

  if constexpr (RES){
    #pragma unroll
    for (int I = 0; I < 2; I++)
      #pragma unroll
      for (int J = 0; J < 2; J++)
        #pragma unroll
        for (int m = 0; m < 4; m++)
          #pragma unroll
          for (int n = 0; n < 2; n++)
            #pragma unroll
            for (int r = 0; r < 4; r++){
              size_t idx = (size_t)(m0 + (I << 7) + (wr << 6) + (m << 4) + (hi << 2) + r) * HIDD
                         + n0 + (J << 7) + (wc << 5) + (n << 4) + ln15;
              outf[idx] = acc[I][J][m][n][r] + bn[J][n] + resid[idx];
            }
  } else {
    float* cw = &sm.cep[wid][0];   // [16][34]
    const int r16 = lane >> 2, cg = lane & 3;
    #pragma unroll
    for (int I = 0; I < 2; I++)
      #pragma unroll
      for (int J = 0; J < 2; J++)
        #pragma unroll
        for (int m = 0; m < 4; m++){
          #pragma unroll
          for (int n = 0; n < 2; n++)
            #pragma unroll
            for (int r = 0; r < 4; r++)
              cw[((hi << 2) + r) * 34 + (n << 4) + ln15] = acc[I][J][m][n][r] + bn[J][n];
          u32 ro[4];
          #pragma unroll
          for (int p = 0; p < 4; p++){
            float v0 = cw[r16 * 34 + (cg << 3) + 2 * p];
            float v1 = cw[r16 * 34 + (cg << 3) + 2 * p + 1];
            ro[p] = (u32)f2bf(v0) | ((u32)f2bf(v1) << 16);
          }
          uint4 o; o.x = ro[0]; o.y = ro[1]; o.z = ro[2]; o.w = ro[3];
          *(uint4*)&outb[(size_t)(m0 + (I << 7) + (wr << 6) + (m << 4) + r16) * HIDD
                         + n0 + (J << 7) + (wc << 5) + (cg << 3)] = o;
        }
  }
  #undef RDA
  #undef RDB
  #undef CLUSTER
  #undef BAR
  #undef VM
}

// ---------------- elu + L2 norm over head_dim (in-place, q) ----------------
__global__ __launch_bounds__(256) void k_elunorm(u16* __restrict__ q){
  size_t idx = (size_t)blockIdx.x * 256 + threadIdx.x;
  uint4 u = ((const uint4*)q)[idx];
  u32 uu[4] = {u.x, u.y, u.z, u.w};
  float e[8]; float ss = 0.f;
  #pragma unroll
  for (int i = 0; i < 4; i++){
    float f0 = bf2f((u16)(uu[i] & 0xffff));
    float f1 = bf2f((u16)(uu[i] >> 16));
    f0 = f0 > 0.f ? f0 : expm1f(f0);
    f1 = f1 > 0.f ? f1 : expm1f(f1);
    e[2*i] = f0; e[2*i+1] = f1;
    ss += f0 * f0 + f1 * f1;
  }
  ss += __shfl_xor(ss, 1); ss += __shfl_xor(ss, 2); ss += __shfl_xor(ss, 4);
  float rn = rsqrtf(ss);
  u32 ro[4];
  #pragma unroll
  for (int i = 0; i < 4; i++)
    ro[i] = (u32)f2bf(e[2*i] * rn) | ((u32)f2bf(e[2*i+1] * rn) << 16);
  uint4 o; o.x = ro[0]; o.y = ro[1]; o.z = ro[2]; o.w = ro[3];
  ((uint4*)q)[idx] = o;
}

// ---------------- transpose [B,S,H,64] -> [B,H,64,S], optional elu+L2norm ----------------
template<int ELU>
__global__ __launch_bounds__(256) void k_transpose(const u16* __restrict__ in, u16* __restrict__ outp){
  __shared__ float tile[64][65];
  __shared__ float pr[64][4];
  __shared__ float rn[64];
  const int sb = blockIdx.x << 6, h = blockIdx.y, b = blockIdx.z;
  const int t = threadIdx.x;
  {
    const int tok = t >> 2, q = t & 3;
    const u16* src = in + (size_t)(b * SQ + sb + tok) * HIDD + (h << 6) + (q << 4);
    uint4 u0 = *(const uint4*)src;
    uint4 u1 = *(const uint4*)(src + 8);
    u32 uu[8] = {u0.x, u0.y, u0.z, u0.w, u1.x, u1.y, u1.z, u1.w};
    float ss = 0.f;
    #pragma unroll
    for (int i = 0; i < 8; i++){
      float f0 = bf2f((u16)(uu[i] & 0xffff));
      float f1 = bf2f((u16)(uu[i] >> 16));
      if (ELU){
        f0 = f0 > 0.f ? f0 : expm1f(f0);
        f1 = f1 > 0.f ? f1 : expm1f(f1);
        ss += f0 * f0 + f1 * f1;
      }
      tile[tok][(q << 4) + 2*i]     = f0;
      tile[tok][(q << 4) + 2*i + 1] = f1;
    }
    if (ELU) pr[tok][q] = ss;
  }
  __syncthreads();
  if (ELU){
    if (t < 64) rn[t] = rsqrtf(pr[t][0] + pr[t][1] + pr[t][2] + pr[t][3]);
    __syncthreads();
  }
  const int d = t >> 2, sq2 = (t & 3) << 4;
  u16* dst = outp + ((size_t)(b * NHQ + h) * 64 + d) * SQ + sb + sq2;
  u32 ro[8];
  #pragma unroll
  for (int i = 0; i < 8; i++){
    float v0 = tile[sq2 + 2*i][d];
    float v1 = tile[sq2 + 2*i + 1][d];
    if (ELU){ v0 *= rn[sq2 + 2*i]; v1 *= rn[sq2 + 2*i + 1]; }
    ro[i] = (u32)f2bf(v0) | ((u32)f2bf(v1) << 16);
  }
  uint4 o0; o0.x = ro[0]; o0.y = ro[1]; o0.z = ro[2]; o0.w = ro[3];
  uint4 o1; o1.x = ro[4]; o1.y = ro[5]; o1.z = ro[6]; o1.w = ro[7];
  *(uint4*)dst = o0;
  *(uint4*)(dst + 8) = o1;
}

// ---------------- kv: per (b,h)  kvT[e][d] = (1/8) * sum_s v[s][e] ek[s][d] ----------------
__global__ __launch_bounds__(256) void k_kv(const u16* __restrict__ vT, const u16* __restrict__ ekT,
                                            u16* __restrict__ kvT){
  const int bh = blockIdx.x;
  const u16* Av = vT  + (size_t)bh * 64 * SQ;
  const u16* Bk = ekT + (size_t)bh * 64 * SQ;
  const int lane = threadIdx.x & 63, wid = threadIdx.x >> 6;
  const int ln15 = lane & 15, hi = lane >> 4;
  f32x4 acc[4][4] = {};
  const int kb = wid << 10;
  for (int ks = 0; ks < 32; ++ks){
    const int k0 = kb + (ks << 5) + (hi << 3);
    bf16x8 af[4], bfr[4];
    #pragma unroll
    for (int m = 0; m < 4; m++) af[m]  = *(const bf16x8*)(Av + (size_t)((m << 4) + ln15) * SQ + k0);
    #pragma unroll
    for (int n = 0; n < 4; n++) bfr[n] = *(const bf16x8*)(Bk + (size_t)((n << 4) + ln15) * SQ + k0);
    #pragma unroll
    for (int m = 0; m < 4; m++)
      #pragma unroll
      for (int n = 0; n < 4; n++)
        acc[m][n] = MFMA(af[m], bfr[n], acc[m][n]);
  }
  __shared__ float red[64][64];
  for (int w = 0; w < 4; ++w){
    if (wid == w){
      #pragma unroll
      for (int m = 0; m < 4; m++)
        #pragma unroll
        for (int n = 0; n < 4; n++)
          #pragma unroll
          for (int r = 0; r < 4; r++){
            int row = (m << 4) + (hi << 2) + r;
            int col = (n << 4) + ln15;
            if (w == 0) red[row][col] = acc[m][n][r];
            else        red[row][col] += acc[m][n][r];
          }
    }
    __syncthreads();
  }
  u16* dst = kvT + (size_t)bh * 4096;
  const int tt = threadIdx.x;
  #pragma unroll
  for (int i = 0; i < 16; i++){
    int idx = tt * 16 + i;
    dst[idx] = f2bf(red[idx >> 6][idx & 63] * 0.125f);
  }
}

// ---------------- ctx: per (b,h,sblock) ctx[s][e] = sum_d eq[s][d] * kv[d][e] ----------------
__global__ __launch_bounds__(256) void k_ctx(const u16* __restrict__ eq, const u16* __restrict__ kvT,
                                             u16* __restrict__ ctx){
  __shared__ u16 Alds[1024 * 8];
  __shared__ u16 Blds[512 * 8];
  const int sb = blockIdx.x << 7;
  const int h = blockIdx.y, b = blockIdx.z;
  const int bh = (b << 4) + h;
  const int t = threadIdx.x, lane = t & 63, wid = t >> 6;
  const int ln15 = lane & 15, hi = lane >> 4;
  {
    uint4 va[4]; uint4 vb[2];
    #pragma unroll
    for (int i = 0; i < 4; i++){
      int c = (wid << 6) + (i << 8) + lane;
      int g = c >> 7, row = c & 127;
      va[i] = *(const uint4*)(eq + (size_t)(b * SQ + sb + row) * HIDD + (h << 6) + g * 8);
    }
    #pragma unroll
    for (int i = 0; i < 2; i++){
      int c = (wid << 6) + (i << 8) + lane;
      int g = c >> 6, row = c & 63;
      vb[i] = *(const uint4*)(kvT + (size_t)bh * 4096 + (row << 6) + g * 8);
    }
    #pragma unroll
    for (int i = 0; i < 4; i++)
      *(uint4*)&Alds[((wid << 6) + (i << 8) + lane) * 8] = va[i];
    #pragma unroll
    for (int i = 0; i < 2; i++)
      *(uint4*)&Blds[((wid << 6) + (i << 8) + lane) * 8] = vb[i];
  }
  __syncthreads();
  f32x4 acc[2][4] = {};
  #pragma unroll
  for (int k2 = 0; k2 < 2; k2++){
    const int g = (k2 << 2) + hi;
    bf16x8 af[2], bfr[4];
    #pragma unroll
    for (int m = 0; m < 2; m++) af[m]  = *(const bf16x8*)&Alds[((g << 7) + (wid << 5) + (m << 4) + ln15) * 8];
    #pragma unroll
    for (int n = 0; n < 4; n++) bfr[n] = *(const bf16x8*)&Blds[((g << 6) + (n << 4) + ln15) * 8];
    #pragma unroll
    for (int m = 0; m < 2; m++)
      #pragma unroll
      for (int n = 0; n < 4; n++)
        acc[m][n] = MFMA(af[m], bfr[n], acc[m][n]);
  }
  #pragma unroll
  for (int m = 0; m < 2; m++)
    #pragma unroll
    for (int n = 0; n < 4; n++)
      #pragma unroll
      for (int r = 0; r < 4; r++){
        int srow = sb + (wid << 5) + (m << 4) + (hi << 2) + r;
        int col  = (n << 4) + ln15;
        ctx[(size_t)(b * SQ + srow) * HIDD + (h << 6) + col] = f2bf(acc[m][n][r]);
      }
}

extern "C" void kernel_launch(void* const* d_in, const int* in_sizes, int n_in,
                              void* d_out, int out_size, void* d_ws, size_t ws_size,
                              hipStream_t stream){
  const float* x   = (const float*)d_in[0];
  const float* lng = (const float*)d_in[2];
  const float* lnb = (const float*)d_in[3];
  const float* Wq  = (const float*)d_in[4];
  const float* bq  = (const float*)d_in[5];
  const float* Wk  = (const float*)d_in[6];
  const float* bk  = (const float*)d_in[7];
  const float* Wv  = (const float*)d_in[8];
  const float* bv  = (const float*)d_in[9];
  const float* Wo  = (const float*)d_in[10];
  const float* bo  = (const float*)d_in[11];
  float* out = (float*)d_out;

  char* w = (char*)d_ws;
  const size_t MB = 1ull << 20;
  u16* wqb  = (u16*)(w + 0   * MB);
  u16* wkb  = (u16*)(w + 2   * MB);
  u16* wvb  = (u16*)(w + 4   * MB);
  u16* wob  = (u16*)(w + 6   * MB);
  u16* xbf  = (u16*)(w + 8   * MB);
  u16* xnbf = (u16*)(w + 72  * MB);
  u16* qb   = (u16*)(w + 136 * MB);
  u16* kb   = (u16*)(w + 200 * MB);
  u16* vb   = (u16*)(w + 264 * MB);
  u16* kvT  = (u16*)(w + 328 * MB);
  u16* ekT = xnbf;
  u16* vT  = xbf;
  u16* ctx = kb;

  k_cast<<<1024, 256, 0, stream>>>(Wq, wqb);
  k_cast<<<1024, 256, 0, stream>>>(Wk, wkb);
  k_cast<<<1024, 256, 0, stream>>>(Wv, wvb);
  k_cast<<<1024, 256, 0, stream>>>(Wo, wob);
  k_ln<<<TOKN, 256, 0, stream>>>(x, lng, lnb, xbf, xnbf);
  k_gemm8p<0><<<512, 512, 0, stream>>>(xnbf, wqb, bq, nullptr, qb, nullptr);
  k_gemm8p<0><<<512, 512, 0, stream>>>(xbf,  wkb, bk, nullptr, kb, nullptr);
  k_gemm8p<0><<<512, 512, 0, stream>>>(xbf,  wvb, bv, nullptr, vb, nullptr);
  k_elunorm<<<16384, 256, 0, stream>>>(qb);
  k_transpose<1><<<dim3(64, 16, 8), 256, 0, stream>>>(kb, ekT);
  k_transpose<0><<<dim3(64, 16, 8), 256, 0, stream>>>(vb, vT);
  k_kv<<<128, 256, 0, stream>>>(vT, ekT, kvT);
  k_ctx<<<dim3(32, 16, 8), 256, 0, stream>>>(qb, kvT, ctx);
  k_gemm8p<1><<<512, 512, 0, stream>>>(ctx, wob, bo, x, nullptr, out);

  (void)in_sizes; (void)n_in; (void)out_size; (void)ws_size;
}

// Round 6
// 863.516 us; speedup vs baseline: 1.3248x; 1.0541x over previous
//
#include <hip/hip_runtime.h>

typedef unsigned short u16;
typedef unsigned int   u32;
typedef __attribute__((ext_vector_type(8))) __bf16 bf16x8;
typedef __attribute__((ext_vector_type(4))) float  f32x4;

#define BQ   8
#define SQ   4096
#define NHQ  16
#define HIDD 1024
#define TOKN 32768

__device__ __forceinline__ u16 f2bf(float f){
  u32 u = __builtin_bit_cast(u32, f);
  u += 0x7fffu + ((u >> 16) & 1u);
  return (u16)(u >> 16);
}
__device__ __forceinline__ float bf2f(u16 h){
  return __builtin_bit_cast(float, (u32)h << 16);
}
__device__ __forceinline__ void gl16(const void* g, void* l){
  __builtin_amdgcn_global_load_lds((const __attribute__((address_space(1))) void*)g,
                                   (__attribute__((address_space(3))) void*)l, 16, 0, 0);
}
#define MFMA(a,b,c) __builtin_amdgcn_mfma_f32_16x16x32_bf16((a),(b),(c),0,0,0)

// ---------------- fp32 -> bf16 cast (weights) ----------------
__global__ __launch_bounds__(256) void k_cast(const float* __restrict__ in, u16* __restrict__ o){
  int i = blockIdx.x * 256 + threadIdx.x;
  float4 v = ((const float4*)in)[i];
  ushort4 r;
  r.x = f2bf(v.x); r.y = f2bf(v.y); r.z = f2bf(v.z); r.w = f2bf(v.w);
  ((ushort4*)o)[i] = r;
}

// ---------------- LayerNorm + cast x / x_norm ----------------
__global__ __launch_bounds__(256) void k_ln(const float* __restrict__ x, const float* __restrict__ g,
    const float* __restrict__ be, u16* __restrict__ xbf, u16* __restrict__ xnbf){
  const int row = blockIdx.x, t = threadIdx.x;
  const float4 v = ((const float4*)(x + (size_t)row * HIDD))[t];
  float s  = v.x + v.y + v.z + v.w;
  float ss = v.x*v.x + v.y*v.y + v.z*v.z + v.w*v.w;
  #pragma unroll
  for (int o = 1; o < 64; o <<= 1){ s += __shfl_xor(s, o); ss += __shfl_xor(ss, o); }
  __shared__ float sm[8];
  const int lane = t & 63, wid = t >> 6;
  if (lane == 0){ sm[wid] = s; sm[wid + 4] = ss; }
  __syncthreads();
  s  = sm[0] + sm[1] + sm[2] + sm[3];
  ss = sm[4] + sm[5] + sm[6] + sm[7];
  const float mu   = s * (1.f / 1024.f);
  const float var  = ss * (1.f / 1024.f) - mu * mu;
  const float rstd = rsqrtf(var + 1e-12f);
  const float4 gg = ((const float4*)g)[t];
  const float4 bb = ((const float4*)be)[t];
  ushort4 xo, no;
  xo.x = f2bf(v.x); no.x = f2bf((v.x - mu) * rstd * gg.x + bb.x);
  xo.y = f2bf(v.y); no.y = f2bf((v.y - mu) * rstd * gg.y + bb.y);
  xo.z = f2bf(v.z); no.z = f2bf((v.z - mu) * rstd * gg.z + bb.z);
  xo.w = f2bf(v.w); no.w = f2bf((v.w - mu) * rstd * gg.w + bb.w);
  ((ushort4*)(xbf  + (size_t)row * HIDD))[t] = xo;
  ((ushort4*)(xnbf + (size_t)row * HIDD))[t] = no;
}

// ---------------- big NT GEMM (r1 structure + XCD/M-major swizzle) ----------------
// C[M, N] = A[M,1024] * W[N,1024]^T + bias (+resid). 128x128 tile, BK=32, 4 waves (2x2),
// global_load_lds staging into granule-major LDS (r1-measured ZERO bank conflicts),
// double-buffered, one __syncthreads per K-step. Output row-stride LDC (fused KV uses 2048).
// bias: cols < nsplit from bias, else bias2[col - nsplit] (block-uniform; tiles never straddle).
template<int RES>
__global__ __launch_bounds__(256) void k_gemm_bt(const u16* __restrict__ A,
    const u16* __restrict__ W, const float* __restrict__ bias, const float* __restrict__ bias2,
    int nsplit, int lgNB, int LDC,
    const float* __restrict__ resid, u16* __restrict__ outb, float* __restrict__ outf){
  __shared__ u16 lds[2][2][4096];   // [buf][A/B][chunk c = g*128 + row, 8 u16 each] = 32 KiB
  const int bid = blockIdx.x;
  const int wg  = ((bid & 7) * ((int)gridDim.x >> 3)) + (bid >> 3);  // XCD-chunked, M-major
  const int m0 = (wg >> lgNB) << 7;
  const int n0 = (wg & ((1 << lgNB) - 1)) << 7;

  const int t = threadIdx.x, lane = t & 63, wid = t >> 6;
  const int ln15 = lane & 15, hi = lane >> 4;
  const int wr = wid >> 1, wc = wid & 1;

  auto stage = [&](int buf, int kt){
    const int k0 = kt << 5;
    #pragma unroll
    for (int i = 0; i < 2; i++){
      int c = (wid << 6) + (i << 8) + lane;
      int g = c >> 7, row = c & 127;
      gl16(A + (size_t)(m0 + row) * HIDD + k0 + g * 8, &lds[buf][0][((wid << 6) + (i << 8)) * 8]);
    }
    #pragma unroll
    for (int i = 0; i < 2; i++){
      int c = (wid << 6) + (i << 8) + lane;
      int g = c >> 7, row = c & 127;
      gl16(W + (size_t)(n0 + row) * HIDD + k0 + g * 8, &lds[buf][1][((wid << 6) + (i << 8)) * 8]);
    }
  };

  f32x4 acc[4][4] = {};
  stage(0, 0);
  asm volatile("s_waitcnt vmcnt(0)" ::: "memory");
  __syncthreads();
  int cur = 0;
  const int NT = HIDD / 32;
  for (int kt = 0; kt < NT; ++kt){
    if (kt + 1 < NT) stage(cur ^ 1, kt + 1);
    const bf16x8* Ab = (const bf16x8*)lds[cur][0];
    const bf16x8* Bb = (const bf16x8*)lds[cur][1];
    bf16x8 af[4], bfr[4];
    const int ci = (hi << 7) + ln15;
    #pragma unroll
    for (int m = 0; m < 4; m++) af[m]  = Ab[ci + (wr << 6) + (m << 4)];
    #pragma unroll
    for (int n = 0; n < 4; n++) bfr[n] = Bb[ci + (wc << 6) + (n << 4)];
    __builtin_amdgcn_s_setprio(1);
    #pragma unroll
    for (int m = 0; m < 4; m++)
      #pragma unroll
      for (int n = 0; n < 4; n++)
        acc[m][n] = MFMA(af[m], bfr[n], acc[m][n]);
    __builtin_amdgcn_s_setprio(0);
    __syncthreads();   // drains vmcnt (staged tile ready) + protects LDS reuse
    cur ^= 1;
  }
  // C/D layout: col = lane&15, row = 4*(lane>>4)+r
  const int rbase = m0 + (wr << 6) + (hi << 2);
  const int cbase = n0 + (wc << 6) + ln15;
  const float* bp = (n0 < nsplit) ? bias : (bias2 - nsplit);
  #pragma unroll
  for (int n = 0; n < 4; n++){
    int col = cbase + (n << 4);
    float bc = bp[col];
    #pragma unroll
    for (int m = 0; m < 4; m++){
      #pragma unroll
      for (int r = 0; r < 4; r++){
        int row = rbase + (m << 4) + r;
        float v = acc[m][n][r] + bc;
        if constexpr (RES)
          outf[(size_t)row * LDC + col] = v + resid[(size_t)row * HIDD + col];
        else
          outb[(size_t)row * LDC + col] = f2bf(v);
      }
    }
  }
}

// ---------------- elu + L2 norm over head_dim (in-place, q) ----------------
__global__ __launch_bounds__(256) void k_elunorm(u16* __restrict__ q){
  size_t idx = (size_t)blockIdx.x * 256 + threadIdx.x;
  uint4 u = ((const uint4*)q)[idx];
  u32 uu[4] = {u.x, u.y, u.z, u.w};
  float e[8]; float ss = 0.f;
  #pragma unroll
  for (int i = 0; i < 4; i++){
    float f0 = bf2f((u16)(uu[i] & 0xffff));
    float f1 = bf2f((u16)(uu[i] >> 16));
    f0 = f0 > 0.f ? f0 : expm1f(f0);
    f1 = f1 > 0.f ? f1 : expm1f(f1);
    e[2*i] = f0; e[2*i+1] = f1;
    ss += f0 * f0 + f1 * f1;
  }
  ss += __shfl_xor(ss, 1); ss += __shfl_xor(ss, 2); ss += __shfl_xor(ss, 4);
  float rn = rsqrtf(ss);
  u32 ro[4];
  #pragma unroll
  for (int i = 0; i < 4; i++)
    ro[i] = (u32)f2bf(e[2*i] * rn) | ((u32)f2bf(e[2*i+1] * rn) << 16);
  uint4 o; o.x = ro[0]; o.y = ro[1]; o.z = ro[2]; o.w = ro[3];
  ((uint4*)q)[idx] = o;
}

// ---------------- transpose [B,S,H,64] (row-stride ld) -> [B,H,64,S], optional elu+L2norm ----------------
template<int ELU>
__global__ __launch_bounds__(256) void k_transpose(const u16* __restrict__ in, int ld,
                                                   u16* __restrict__ outp){
  __shared__ float tile[64][65];
  __shared__ float pr[64][4];
  __shared__ float rn[64];
  const int sb = blockIdx.x << 6, h = blockIdx.y, b = blockIdx.z;
  const int t = threadIdx.x;
  {
    const int tok = t >> 2, q = t & 3;
    const u16* src = in + (size_t)(b * SQ + sb + tok) * ld + (h << 6) + (q << 4);
    uint4 u0 = *(const uint4*)src;
    uint4 u1 = *(const uint4*)(src + 8);
    u32 uu[8] = {u0.x, u0.y, u0.z, u0.w, u1.x, u1.y, u1.z, u1.w};
    float ss = 0.f;
    #pragma unroll
    for (int i = 0; i < 8; i++){
      float f0 = bf2f((u16)(uu[i] & 0xffff));
      float f1 = bf2f((u16)(uu[i] >> 16));
      if (ELU){
        f0 = f0 > 0.f ? f0 : expm1f(f0);
        f1 = f1 > 0.f ? f1 : expm1f(f1);
        ss += f0 * f0 + f1 * f1;
      }
      tile[tok][(q << 4) + 2*i]     = f0;
      tile[tok][(q << 4) + 2*i + 1] = f1;
    }
    if (ELU) pr[tok][q] = ss;
  }
  __syncthreads();
  if (ELU){
    if (t < 64) rn[t] = rsqrtf(pr[t][0] + pr[t][1] + pr[t][2] + pr[t][3]);
    __syncthreads();
  }
  const int d = t >> 2, sq2 = (t & 3) << 4;
  u16* dst = outp + ((size_t)(b * NHQ + h) * 64 + d) * SQ + sb + sq2;
  u32 ro[8];
  #pragma unroll
  for (int i = 0; i < 8; i++){
    float v0 = tile[sq2 + 2*i][d];
    float v1 = tile[sq2 + 2*i + 1][d];
    if (ELU){ v0 *= rn[sq2 + 2*i]; v1 *= rn[sq2 + 2*i + 1]; }
    ro[i] = (u32)f2bf(v0) | ((u32)f2bf(v1) << 16);
  }
  uint4 o0; o0.x = ro[0]; o0.y = ro[1]; o0.z = ro[2]; o0.w = ro[3];
  uint4 o1; o1.x = ro[4]; o1.y = ro[5]; o1.z = ro[6]; o1.w = ro[7];
  *(uint4*)dst = o0;
  *(uint4*)(dst + 8) = o1;
}

// ---------------- kv: per (b,h)  kvT[e][d] = (1/8) * sum_s v[s][e] ek[s][d] ----------------
__global__ __launch_bounds__(256) void k_kv(const u16* __restrict__ vT, const u16* __restrict__ ekT,
                                            u16* __restrict__ kvT){
  const int bh = blockIdx.x;
  const u16* Av = vT  + (size_t)bh * 64 * SQ;
  const u16* Bk = ekT + (size_t)bh * 64 * SQ;
  const int lane = threadIdx.x & 63, wid = threadIdx.x >> 6;
  const int ln15 = lane & 15, hi = lane >> 4;
  f32x4 acc[4][4] = {};
  const int kb = wid << 10;
  for (int ks = 0; ks < 32; ++ks){
    const int k0 = kb + (ks << 5) + (hi << 3);
    bf16x8 af[4], bfr[4];
    #pragma unroll
    for (int m = 0; m < 4; m++) af[m]  = *(const bf16x8*)(Av + (size_t)((m << 4) + ln15) * SQ + k0);
    #pragma unroll
    for (int n = 0; n < 4; n++) bfr[n] = *(const bf16x8*)(Bk + (size_t)((n << 4) + ln15) * SQ + k0);
    #pragma unroll
    for (int m = 0; m < 4; m++)
      #pragma unroll
      for (int n = 0; n < 4; n++)
        acc[m][n] = MFMA(af[m], bfr[n], acc[m][n]);
  }
  __shared__ float red[64][64];
  for (int w = 0; w < 4; ++w){
    if (wid == w){
      #pragma unroll
      for (int m = 0; m < 4; m++)
        #pragma unroll
        for (int n = 0; n < 4; n++)
          #pragma unroll
          for (int r = 0; r < 4; r++){
            int row = (m << 4) + (hi << 2) + r;
            int col = (n << 4) + ln15;
            if (w == 0) red[row][col] = acc[m][n][r];
            else        red[row][col] += acc[m][n][r];
          }
    }
    __syncthreads();
  }
  u16* dst = kvT + (size_t)bh * 4096;
  const int tt = threadIdx.x;
  #pragma unroll
  for (int i = 0; i < 16; i++){
    int idx = tt * 16 + i;
    dst[idx] = f2bf(red[idx >> 6][idx & 63] * 0.125f);
  }
}

// ---------------- ctx: per (b,h,sblock) ctx[s][e] = sum_d eq[s][d] * kv[d][e] ----------------
__global__ __launch_bounds__(256) void k_ctx(const u16* __restrict__ eq, const u16* __restrict__ kvT,
                                             u16* __restrict__ ctx){
  __shared__ u16 Alds[1024 * 8];
  __shared__ u16 Blds[512 * 8];
  const int sb = blockIdx.x << 7;
  const int h = blockIdx.y, b = blockIdx.z;
  const int bh = (b << 4) + h;
  const int t = threadIdx.x, lane = t & 63, wid = t >> 6;
  const int ln15 = lane & 15, hi = lane >> 4;
  {
    uint4 va[4]; uint4 vb[2];
    #pragma unroll
    for (int i = 0; i < 4; i++){
      int c = (wid << 6) + (i << 8) + lane;
      int g = c >> 7, row = c & 127;
      va[i] = *(const uint4*)(eq + (size_t)(b * SQ + sb + row) * HIDD + (h << 6) + g * 8);
    }
    #pragma unroll
    for (int i = 0; i < 2; i++){
      int c = (wid << 6) + (i << 8) + lane;
      int g = c >> 6, row = c & 63;
      vb[i] = *(const uint4*)(kvT + (size_t)bh * 4096 + (row << 6) + g * 8);
    }
    #pragma unroll
    for (int i = 0; i < 4; i++)
      *(uint4*)&Alds[((wid << 6) + (i << 8) + lane) * 8] = va[i];
    #pragma unroll
    for (int i = 0; i < 2; i++)
      *(uint4*)&Blds[((wid << 6) + (i << 8) + lane) * 8] = vb[i];
  }
  __syncthreads();
  f32x4 acc[2][4] = {};
  #pragma unroll
  for (int k2 = 0; k2 < 2; k2++){
    const int g = (k2 << 2) + hi;
    bf16x8 af[2], bfr[4];
    #pragma unroll
    for (int m = 0; m < 2; m++) af[m]  = *(const bf16x8*)&Alds[((g << 7) + (wid << 5) + (m << 4) + ln15) * 8];
    #pragma unroll
    for (int n = 0; n < 4; n++) bfr[n] = *(const bf16x8*)&Blds[((g << 6) + (n << 4) + ln15) * 8];
    #pragma unroll
    for (int m = 0; m < 2; m++)
      #pragma unroll
      for (int n = 0; n < 4; n++)
        acc[m][n] = MFMA(af[m], bfr[n], acc[m][n]);
  }
  #pragma unroll
  for (int m = 0; m < 2; m++)
    #pragma unroll
    for (int n = 0; n < 4; n++)
      #pragma unroll
      for (int r = 0; r < 4; r++){
        int srow = sb + (wid << 5) + (m << 4) + (hi << 2) + r;
        int col  = (n << 4) + ln15;
        ctx[(size_t)(b * SQ + srow) * HIDD + (h << 6) + col] = f2bf(acc[m][n][r]);
      }
}

extern "C" void kernel_launch(void* const* d_in, const int* in_sizes, int n_in,
                              void* d_out, int out_size, void* d_ws, size_t ws_size,
                              hipStream_t stream){
  const float* x   = (const float*)d_in[0];
  const float* lng = (const float*)d_in[2];
  const float* lnb = (const float*)d_in[3];
  const float* Wq  = (const float*)d_in[4];
  const float* bq  = (const float*)d_in[5];
  const float* Wk  = (const float*)d_in[6];
  const float* bk  = (const float*)d_in[7];
  const float* Wv  = (const float*)d_in[8];
  const float* bv  = (const float*)d_in[9];
  const float* Wo  = (const float*)d_in[10];
  const float* bo  = (const float*)d_in[11];
  float* out = (float*)d_out;

  char* w = (char*)d_ws;
  const size_t MB = 1ull << 20;
  u16* wqb  = (u16*)(w + 0   * MB);   // 2 MiB
  u16* wkvb = (u16*)(w + 2   * MB);   // 4 MiB: [Wk; Wv] stacked, [2048][1024]
  u16* wob  = (u16*)(w + 6   * MB);   // 2 MiB
  u16* xbf  = (u16*)(w + 8   * MB);   // 64 MiB
  u16* xnbf = (u16*)(w + 72  * MB);   // 64 MiB
  u16* qb   = (u16*)(w + 136 * MB);   // 64 MiB
  u16* kvb  = (u16*)(w + 200 * MB);   // 128 MiB: [32768][2048] (K cols 0..1023, V cols 1024..2047)
  u16* kvT  = (u16*)(w + 328 * MB);   // 1 MiB
  // aliases (stream-ordered lifetimes)
  u16* ekT = xnbf;  // xnbf dead after Q GEMM
  u16* vT  = xbf;   // xbf dead after KV GEMM
  u16* ctx = kvb;   // kvb dead after transposes

  k_cast<<<1024, 256, 0, stream>>>(Wq, wqb);
  k_cast<<<1024, 256, 0, stream>>>(Wk, wkvb);
  k_cast<<<1024, 256, 0, stream>>>(Wv, wkvb + 1024 * 1024);
  k_cast<<<1024, 256, 0, stream>>>(Wo, wob);
  k_ln<<<TOKN, 256, 0, stream>>>(x, lng, lnb, xbf, xnbf);
  // Q: M=32768, N=1024 (8 N-tiles, lgNB=3), grid 2048
  k_gemm_bt<0><<<2048, 256, 0, stream>>>(xnbf, wqb, bq, bq, 1 << 30, 3, 1024,
                                         nullptr, qb, nullptr);
  // fused K+V: N=2048 (16 N-tiles, lgNB=4), grid 4096, bias split at 1024
  k_gemm_bt<0><<<4096, 256, 0, stream>>>(xbf, wkvb, bk, bv, 1024, 4, 2048,
                                         nullptr, kvb, nullptr);
  k_elunorm<<<16384, 256, 0, stream>>>(qb);
  k_transpose<1><<<dim3(64, 16, 8), 256, 0, stream>>>(kvb,        2048, ekT);
  k_transpose<0><<<dim3(64, 16, 8), 256, 0, stream>>>(kvb + 1024, 2048, vT);
  k_kv<<<128, 256, 0, stream>>>(vT, ekT, kvT);
  k_ctx<<<dim3(32, 16, 8), 256, 0, stream>>>(qb, kvT, ctx);
  // out: residual + fp32 out
  k_gemm_bt<1><<<2048, 256, 0, stream>>>(ctx, wob, bo, bo, 1 << 30, 3, 1024,
                                         x, nullptr, out);

  (void)in_sizes; (void)n_in; (void)out_size; (void)ws_size;
}